// Round 16
// baseline (107.127 us; speedup 1.0000x reference)
//
#include <hip/hip_runtime.h>
#include <stdint.h>

typedef __bf16 bf16_t;
typedef bf16_t bf16x8 __attribute__((ext_vector_type(8)));
typedef float f32x2 __attribute__((ext_vector_type(2)));
typedef float f32x4 __attribute__((ext_vector_type(4)));
typedef uint32_t u32x4 __attribute__((ext_vector_type(4)));
typedef uint16_t u16x8 __attribute__((ext_vector_type(8)));

union FragU { u32x4 u; bf16x8 v; u16x8 s; };

__device__ __forceinline__ uint16_t f2bf_rne(float f) {
  uint32_t u = __float_as_uint(f);
  return (uint16_t)((u + 0x7fffu + ((u >> 16) & 1u)) >> 16);
}

// ---------------------------------------------------------------------------
// Kernel 1: pack W (512x52 f32) into MFMA B-fragment layout, single bf16.
// B-frag for mfma_f32_16x16x32_bf16: lane l holds B[k][n], n = nt*16+(l&15),
// k = c32*32 + (l>>4)*8 + j. N padded 52->64. ws: wf[4096] u32x4 (64 KB).
// ---------------------------------------------------------------------------
__global__ __launch_bounds__(256) void pack_w_kernel(
    const float* __restrict__ W, u32x4* __restrict__ wf) {
  int idx = blockIdx.x * 256 + threadIdx.x;
  if (idx >= 4096) return;
  int lane = idx & 63;
  int nt   = (idx >> 6) & 3;
  int ks   = idx >> 8;
  int n  = nt * 16 + (lane & 15);
  int kb = ks * 32 + (lane >> 4) * 8;
  FragU hi;
#pragma unroll
  for (int j = 0; j < 8; ++j) {
    float w = (n < 52) ? W[(kb + j) * 52 + n] : 0.0f;
    hi.s[j] = f2bf_rne(w);
  }
  wf[idx] = hi.u;
}

#define MFMA16(a, b, c) __builtin_amdgcn_mfma_f32_16x16x32_bf16((a), (b), (c), 0, 0, 0)

// ---------------------------------------------------------------------------
// Kernel 2: fused GEMM + bias + softmax(13) + rule mix — HALF-CHUNK RING.
// 256 B granule (BK=64) kept; each chunk split into 2 half-chunks by M-tile
// (16 rows x 256 B = 4 KB). 3-buffer ring/wave = 12 KB -> 48 KB/block ->
// 3 blocks/CU, 12 waves/CU (+50% TLP vs r15 at same granule).
// Half-chunk q = 2*ks + mt, q = 0..15. Issue after proc(q): stage(q+3);
// after odd q: B(ks+2) (both halves of ks read bh[ks&1]). Uniform steady
// wait vmcnt(16) (tail 4/0). B register double-buffer.
// ---------------------------------------------------------------------------
__global__ __launch_bounds__(256, 3) void raven_main_kernel(
    const float* __restrict__ z, const float* __restrict__ xq,
    const u32x4* __restrict__ wfh,
    const float* __restrict__ bias, float* __restrict__ out) {
  __shared__ __align__(16) unsigned char smem[49152];  // staging / logits_t union
  __shared__ float lds_bias[52];

  const int tid  = threadIdx.x;
  const int wave = tid >> 6;
  const int lane = tid & 63;
  const int r  = lane & 15;   // A row within 16-tile / C col
  const int kg = lane >> 4;   // k-group (8 contiguous k per lane)

  if (tid < 52) lds_bias[tid] = bias[tid];

  const long long brow = (long long)blockIdx.x * 128;
  const long long wrow = brow + (long long)wave * 32;
  const float* zb = z + wrow * 512;

  unsigned char* stg = smem + wave * 12288;  // [3][4096] ring

  // staging: instr i covers local rows i*4 + (lane>>4), 16 lanes x 16 B;
  // source slot pre-swizzled: s' = (lane&15) ^ (srow&7); read XORs the same.
  const int rloc4 = lane >> 4;   // 0..3: row within instr
  const int slot  = lane & 15;   // 16 B slot within the 256 B row-run

  f32x4 acc[2][4];
#pragma unroll
  for (int mt = 0; mt < 2; ++mt)
#pragma unroll
    for (int nt = 0; nt < 4; ++nt) {
      f32x4 zv = {0.0f, 0.0f, 0.0f, 0.0f};
      acc[mt][nt] = zv;
    }

#define STAGE_HC(p_)                                                            \
  {                                                                             \
    unsigned char* b_ = stg + ((p_) % 3) * 4096;                                \
    const int mt_ = (p_) & 1, ksq_ = (p_) >> 1;                                 \
    _Pragma("unroll")                                                           \
    for (int i_ = 0; i_ < 4; ++i_) {                                            \
      const int srow_ = i_ * 4 + rloc4;                                         \
      const int foff_ = 4 * (slot ^ (srow_ & 7));                               \
      const float* g_ = zb + (mt_ * 16 + srow_) * 512 + ksq_ * 64 + foff_;      \
      __builtin_amdgcn_global_load_lds(                                         \
          (const __attribute__((address_space(1))) void*)g_,                    \
          (__attribute__((address_space(3))) void*)(b_ + i_ * 1024),            \
          16, 0, 0);                                                            \
    }                                                                           \
  }

#define LOADB(ks_, set_)                                                        \
  {                                                                             \
    _Pragma("unroll")                                                           \
    for (int ksub_ = 0; ksub_ < 2; ++ksub_) {                                   \
      const u32x4* p_ = wfh + (2 * (ks_) + ksub_) * 256 + lane;                 \
      _Pragma("unroll")                                                         \
      for (int nt_ = 0; nt_ < 4; ++nt_)                                         \
        bh[set_][ksub_ * 4 + nt_].u = p_[nt_ * 64];                             \
    }                                                                           \
  }

  FragU bh[2][8];

  // prologue FIFO: B0(8) < s0(4) < s1(4) < B1(8) < s2(4)
  LOADB(0, 0);
  STAGE_HC(0);
  STAGE_HC(1);
  LOADB(1, 1);
  STAGE_HC(2);

  const int swz = (r & 7) << 4;

#pragma unroll
  for (int q = 0; q < 16; ++q) {
    const int ks = q >> 1, mt = q & 1, cs = ks & 1;
    const unsigned char* buf = stg + (q % 3) * 4096;

    // FIFO-derived waits: q<=13 -> vmcnt(16); q=14 -> 4; q=15 -> 0.
    if (q <= 13)      asm volatile("s_waitcnt vmcnt(16)" ::: "memory");
    else if (q == 14) asm volatile("s_waitcnt vmcnt(4)"  ::: "memory");
    else              asm volatile("s_waitcnt vmcnt(0)"  ::: "memory");
    __builtin_amdgcn_sched_barrier(0);

    // A-frags: 16-row buffer, row r, 256 B stride, XOR swizzle (as r15)
    const unsigned char* cm = buf + r * 256;
    FragU h[2];
#pragma unroll
    for (int ksub = 0; ksub < 2; ++ksub) {
      f32x4 a0 = *(const f32x4*)(cm + ((ksub * 128 + kg * 32) ^ swz));
      f32x4 a1 = *(const f32x4*)(cm + ((ksub * 128 + kg * 32 + 16) ^ swz));
#pragma unroll
      for (int j = 0; j < 4; ++j) {
        h[ksub].v[j]     = (bf16_t)a0[j];
        h[ksub].v[4 + j] = (bf16_t)a1[j];
      }
    }

#pragma unroll
    for (int ksub = 0; ksub < 2; ++ksub)
#pragma unroll
      for (int nt = 0; nt < 4; ++nt)
        acc[mt][nt] = MFMA16(h[ksub].v, bh[cs][ksub * 4 + nt].v, acc[mt][nt]);
    __builtin_amdgcn_sched_barrier(0);

    // issue next operands (ds_reads of buf retired above -> safe overwrite)
    if (q <= 12) STAGE_HC(q + 3);
    if ((q & 1) && (ks + 2) <= 7) LOADB(ks + 2, (ks + 2) & 1);
  }
#undef STAGE_HC
#undef LOADB

  // staging area is dead only after ALL waves finish their K-loop
  __syncthreads();

  // TRANSPOSED logits tile: lds_t[col][local_row], stride 132 (pad 4).
  // C layout: col = nt*16 + r, row = wave*32 + mt*16 + kg*4 + i.
  float (*lds_t)[132] = (float(*)[132])smem;
#pragma unroll
  for (int mt = 0; mt < 2; ++mt)
#pragma unroll
    for (int nt = 0; nt < 4; ++nt)
      *(f32x4*)&lds_t[nt * 16 + r][wave * 32 + mt * 16 + kg * 4] = acc[mt][nt];

  __syncthreads();

  // Epilogue over ALL 256 threads: thread t -> row = t>>1, groups
  // gp = (t&1)*2 .. gp+1. Per group: softmax(13) + rule mix.
  // rules = [a, b-2, b-1, b+1, b+2, a-b, a+b, min, max, b+2, b+1, b-2, b-1]
  {
    const int row = tid >> 1;
    const int gp  = (tid & 1) * 2;
    const long long grow = brow + row;
    f32x2 res;
#pragma unroll
    for (int gi = 0; gi < 2; ++gi) {
      const int g = gp + gi;
      float a  = xq[grow * 8 + g];
      float bq = xq[grow * 8 + 4 + g];
      float l[13];
      float m = -1e30f;
#pragma unroll
      for (int u = 0; u < 13; ++u) {
        l[u] = lds_t[g * 13 + u][row] + lds_bias[g * 13 + u];
        m = fmaxf(m, l[u]);
      }
      float s = 0.0f;
#pragma unroll
      for (int u = 0; u < 13; ++u) {
        float e = __expf(l[u] - m);
        l[u] = e;
        s += e;
      }
      float num = a * l[0]
                + (bq - 2.0f) * (l[1] + l[11])
                + (bq - 1.0f) * (l[2] + l[12])
                + (bq + 1.0f) * (l[3] + l[10])
                + (bq + 2.0f) * (l[4] + l[9])
                + (a - bq) * l[5]
                + (a + bq) * l[6]
                + fminf(a, bq) * l[7]
                + fmaxf(a, bq) * l[8];
      res[gi] = num / s;
    }
    *(f32x2*)(out + grow * 4 + gp) = res;
  }
}

extern "C" void kernel_launch(void* const* d_in, const int* in_sizes, int n_in,
                              void* d_out, int out_size, void* d_ws, size_t ws_size,
                              hipStream_t stream) {
  const float* z    = (const float*)d_in[0];  // (B, 512)
  const float* xq   = (const float*)d_in[1];  // (B, 2, 4)
  const float* W    = (const float*)d_in[2];  // (512, 52)
  const float* bias = (const float*)d_in[3];  // (52,)
  float* out = (float*)d_out;                 // (B, 1, 4)

  const int B = in_sizes[0] / 512;            // 262144

  u32x4* wf = (u32x4*)d_ws;

  hipLaunchKernelGGL(pack_w_kernel, dim3(16), dim3(256), 0, stream, W, wf);

  const int blocks = B / 128;                 // 2048
  hipLaunchKernelGGL(raven_main_kernel, dim3(blocks), dim3(256), 0, stream,
                     z, xq, (const u32x4*)wf, bias, out);
}